// Round 6
// baseline (183.794 us; speedup 1.0000x reference)
//
#include <hip/hip_runtime.h>

#define NB 32
#define WAVES_PER_BLOCK 4

__device__ __forceinline__ float clamp01(float x) {
    return fminf(fmaxf(x, 0.0f), 1.0f);
}

// Pass 1 + EPGL for one token: lane (i = lw&31, half) owns W[i][c0..c0+15]
// in wrow[4] (static-indexed), reads h via LDS broadcast, merges the two
// column-halves with one __shfl_xor(32) set, returns h_new[i].
__device__ __forceinline__ float4 token_pass1(
    const float* __restrict__ shin, const float4* wrow,
    int i, int c0, float sti)
{
    const float* wf = (const float*)wrow;   // unrolled -> compile-time indices
    float accE = 0.f, accP = 0.f, accG = 0.f, accL = 0.f, tot = 0.f;
    #pragma unroll
    for (int t = 0; t < 16; ++t) {
        const int j = c0 + t;
        float w = wf[t];
        w = (j == i) ? 0.0f : w;                 // zero self-connection
        const float4 hj = *(const float4*)&shin[j * 4];   // broadcast read
        accE = fmaf(w, hj.x, accE);
        accP = fmaf(w, hj.y, accP);
        accG = fmaf(w, hj.z, accG);
        accL = fmaf(w, hj.w, accL);
        tot += w;
    }
    accE += __shfl_xor(accE, 32);
    accP += __shfl_xor(accP, 32);
    accG += __shfl_xor(accG, 32);
    accL += __shfl_xor(accL, 32);
    tot  += __shfl_xor(tot,  32);

    const float inv = 1.0f / (tot + 1e-8f);
    const float En = accE * inv, Pn = accP * inv, Gn = accG * inv, Ln = accL * inv;

    const float4 hi = *(const float4*)&shin[i * 4];
    const float E = hi.x, P = hi.y, G = hi.z, L = hi.w;

    const float E_new = clamp01(E + 0.3f * sti - 0.4f * P - 0.2f * G);
    const float P_new = clamp01(P + 0.5f * sti + 0.3f * (Pn - P) - 0.2f * E);
    const float G_new = clamp01(G + 0.4f * E * (1.0f - P) + 0.2f * (Gn - G) - 0.3f * P);
    const float good  = 0.5f * En + 0.5f * Gn;
    const float L_new = clamp01(L + 0.4f * good + 0.3f * (Ln - L) - 0.3f * P);
    return make_float4(E_new, P_new, G_new, L_new);
}

// Pass 2 for one token: W_new for the lane's 16 owned (i, j) entries.
__device__ __forceinline__ void token_pass2(
    const float* __restrict__ shn, const float4* wrow, float4 hr,
    int i, int c0, float4* __restrict__ outWr)
{
    const float* wf = (const float*)wrow;
    const float Lr = hr.w;
    #pragma unroll
    for (int e = 0; e < 4; ++e) {
        float4 res;
        float* resp = &res.x;
        #pragma unroll
        for (int q = 0; q < 4; ++q) {
            const int t = 4 * e + q;
            const int j = c0 + t;
            const float4 hj = *(const float4*)&shn[j * 4];  // broadcast read
            const float dx = hr.x - hj.x;
            const float dy = hr.y - hj.y;
            const float dz = hr.z - hj.z;
            const float dw = hr.w - hj.w;
            const float sq = dx * dx + dy * dy + dz * dz + dw * dw;
            const float dist = sqrtf(sq);                   // sqrt(0)=0 matches ref
            const float mutual = 0.5f * (Lr + hj.w);
            float wn = 0.95f * wf[t] + 0.1f * mutual * dist;
            wn = clamp01(wn);
            resp[q] = (j == i) ? 0.0f : wn;                 // zero diagonal
        }
        outWr[e] = res;
    }
}

// TWO tokens per wave (A, B): two fully independent pipelines whose global
// loads all issue up front, so B's loads are in flight under A's compute —
// software ILP to hide memory latency instead of relying on occupancy.
// 8 tokens per 256-thread block. All LDS wave-private -> no __syncthreads.
// launch_bounds(256,6): VGPR cap 85, 24 waves/CU = 48 token pipelines/CU.
__global__ __launch_bounds__(256, 6) void biotoken_step(
    const float* __restrict__ h,
    const float* __restrict__ W,
    const float* __restrict__ stim,
    float* __restrict__ out_h,
    float* __restrict__ out_W)
{
    const int lw   = threadIdx.x & 63;    // lane in wave
    const int wave = threadIdx.x >> 6;    // 0..3
    const int tokA = (blockIdx.x * WAVES_PER_BLOCK + wave) * 2;
    const int i    = lw & 31;             // row this lane owns
    const int half = lw >> 5;             // column-half this lane owns
    const int c0   = half * 16;           // first owned column

    __shared__ float s_hin [WAVES_PER_BLOCK][2][NB * 4];
    __shared__ float s_hnew[WAVES_PER_BLOCK][2][NB * 4];

    // ---- stage: all global loads for BOTH tokens issued up front ----
    const float* WtA = W + (size_t)tokA * (NB * NB);
    const float4* wpA = (const float4*)(WtA + i * NB + c0);
    const float4* wpB = (const float4*)(WtA + NB * NB + i * NB + c0);
    float4 wA[4], wB[4];
    wA[0] = wpA[0]; wA[1] = wpA[1]; wA[2] = wpA[2]; wA[3] = wpA[3];
    wB[0] = wpB[0]; wB[1] = wpB[1]; wB[2] = wpB[2]; wB[3] = wpB[3];

    // h: lanes 0-31 stage token A's 32 float4s, lanes 32-63 token B's
    ((float4*)s_hin[wave][half])[i] =
        ((const float4*)(h + (size_t)(tokA + half) * (NB * 4)))[i];
    const float stiA = stim[(size_t)tokA * NB + i];           // 128B broadcast
    const float stiB = stim[(size_t)(tokA + 1) * NB + i];
    __builtin_amdgcn_wave_barrier();      // scheduling fence only

    // ---- pass 1 + EPGL, pipeline A then B (B loads in flight under A) ----
    const float4 hrA = token_pass1(s_hin[wave][0], wA, i, c0, stiA);
    const float4 hrB = token_pass1(s_hin[wave][1], wB, i, c0, stiB);

    // publish h_new: half 0 lanes own token A's row i, half 1 token B's
    const float4 outv = half ? hrB : hrA;
    ((float4*)s_hnew[wave][half])[i] = outv;
    ((float4*)(out_h + (size_t)(tokA + half) * (NB * 4)))[i] = outv;
    __builtin_amdgcn_wave_barrier();      // scheduling fence only

    // ---- pass 2: W_new for both tokens ----
    token_pass2(s_hnew[wave][0], wA, hrA, i, c0,
                (float4*)(out_W + (size_t)tokA * (NB * NB) + i * NB + c0));
    token_pass2(s_hnew[wave][1], wB, hrB, i, c0,
                (float4*)(out_W + (size_t)(tokA + 1) * (NB * NB) + i * NB + c0));
}

extern "C" void kernel_launch(void* const* d_in, const int* in_sizes, int n_in,
                              void* d_out, int out_size, void* d_ws, size_t ws_size,
                              hipStream_t stream) {
    const float* h    = (const float*)d_in[0];  // [8,2048,32,4]
    const float* W    = (const float*)d_in[1];  // [8,2048,32,32]
    const float* stim = (const float*)d_in[2];  // [8,2048,32]

    const int tokens = in_sizes[2] / NB;        // 16384
    float* out_h = (float*)d_out;               // [8,2048,32,4]
    float* out_W = (float*)d_out + (size_t)tokens * NB * 4;  // [8,2048,32,32]

    const int blocks = tokens / (WAVES_PER_BLOCK * 2); // 2048
    biotoken_step<<<blocks, 256, 0, stream>>>(h, W, stim, out_h, out_W);
}

// Round 7
// 135.379 us; speedup vs baseline: 1.3576x; 1.3576x over previous
//
#include <hip/hip_runtime.h>

#define NB 32
#define WAVES_PER_BLOCK 2   // 128-thread blocks: small LDS footprint, fine-grain dispatch

__device__ __forceinline__ float clamp01(float x) {
    return fminf(fmaxf(x, 0.0f), 1.0f);
}

// One 64-lane wave per (b,s) token; 2 tokens per 128-thread block.
// Round-1 champion dataflow: W loaded in m-layout (fully coalesced 1KB/instr),
// scattered to a padded LDS copy (row stride 33 -> conflict-free row reads)
// for the inflow pass, and kept in registers for the W_new pass (same lane
// owns the same 4 float4s in both passes). All LDS is wave-private, so the
// block-wide __syncthreads of round 1 are replaced by wave scheduling fences:
// per-wave DS ops are in-order and the compiler inserts lgkmcnt waits.
// LDS = 10.5 KB/block -> ~15 blocks/CU = 30 waves/CU (vs 21.5 KB / 7 blocks).
__global__ __launch_bounds__(128, 8) void biotoken_step(
    const float* __restrict__ h,
    const float* __restrict__ W,
    const float* __restrict__ stim,
    float* __restrict__ out_h,
    float* __restrict__ out_W)
{
    const int lw    = threadIdx.x & 63;   // lane in wave
    const int wave  = threadIdx.x >> 6;   // 0..1
    const int token = blockIdx.x * WAVES_PER_BLOCK + wave;
    const int i     = lw & 31;            // row this lane owns in pass 1
    const int half  = lw >> 5;            // j-range selector in pass 1

    __shared__ float s_hin [WAVES_PER_BLOCK][NB * 4];
    __shared__ float s_hnew[WAVES_PER_BLOCK][NB * 4];
    __shared__ float s_W   [WAVES_PER_BLOCK][NB * 33];   // +1 pad per row

    const float4* Wt = (const float4*)(W + (size_t)token * (NB * NB)); // 256 float4
    const float4* ht = (const float4*)(h + (size_t)token * (NB * 4));  // 32 float4

    // ---- stage: W -> registers (and padded LDS), h -> LDS, stim -> reg ----
    // float4 index m = k*64+lw : row = m>>3, col = (m&7)*4  (coalesced loads)
    float4 wr[4];
    wr[0] = Wt[0 * 64 + lw];
    wr[1] = Wt[1 * 64 + lw];
    wr[2] = Wt[2 * 64 + lw];
    wr[3] = Wt[3 * 64 + lw];
    const float sti = stim[(size_t)token * NB + i];   // both halves same 128B

    if (lw < NB) {
        ((float4*)s_hin[wave])[lw] = ht[lw];
    }

    {
        float* sw = s_W[wave];
        const int g = lw >> 3;          // row within 8-row group
        const int c = (lw & 7) * 4;     // starting col
        #pragma unroll
        for (int k = 0; k < 4; ++k) {
            const int r = k * 8 + g;
            const float* wp = (const float*)&wr[k];
            sw[r * 33 + c + 0] = wp[0];
            sw[r * 33 + c + 1] = wp[1];
            sw[r * 33 + c + 2] = wp[2];
            sw[r * 33 + c + 3] = wp[3];
        }
    }
    __builtin_amdgcn_wave_barrier();    // scheduling fence only (wave-private LDS)

    // ---- pass 1: inflow. lane (i, half) sums 16 j's ----
    const float* sw   = s_W[wave];
    const float* shin = s_hin[wave];

    float accE = 0.f, accP = 0.f, accG = 0.f, accL = 0.f, tot = 0.f;
    #pragma unroll
    for (int t = 0; t < 16; ++t) {
        const int j = half * 16 + t;
        float w = sw[i * 33 + j];
        w = (j == i) ? 0.0f : w;                 // zero self-connection
        const float4 hj = *(const float4*)&shin[j * 4];   // broadcast read
        accE = fmaf(w, hj.x, accE);
        accP = fmaf(w, hj.y, accP);
        accG = fmaf(w, hj.z, accG);
        accL = fmaf(w, hj.w, accL);
        tot += w;
    }
    accE += __shfl_xor(accE, 32);
    accP += __shfl_xor(accP, 32);
    accG += __shfl_xor(accG, 32);
    accL += __shfl_xor(accL, 32);
    tot  += __shfl_xor(tot,  32);

    const float inv = 1.0f / (tot + 1e-8f);
    const float En = accE * inv, Pn = accP * inv, Gn = accG * inv, Ln = accL * inv;

    // ---- EPGL state update (computed redundantly in both halves) ----
    const float4 hi = *(const float4*)&shin[i * 4];
    const float E = hi.x, P = hi.y, G = hi.z, L = hi.w;

    const float E_new = clamp01(E + 0.3f * sti - 0.4f * P - 0.2f * G);
    const float P_new = clamp01(P + 0.5f * sti + 0.3f * (Pn - P) - 0.2f * E);
    const float G_new = clamp01(G + 0.4f * E * (1.0f - P) + 0.2f * (Gn - G) - 0.3f * P);
    const float good  = 0.5f * En + 0.5f * Gn;
    const float L_new = clamp01(L + 0.4f * good + 0.3f * (Ln - L) - 0.3f * P);

    if (half == 0) {
        const float4 hn = make_float4(E_new, P_new, G_new, L_new);
        ((float4*)s_hnew[wave])[i] = hn;
        ((float4*)(out_h + (size_t)token * (NB * 4)))[i] = hn;
    }
    __builtin_amdgcn_wave_barrier();    // scheduling fence only

    // ---- pass 2: W_new. pairwise distance + update, W from registers ----
    const float* shn = s_hnew[wave];
    float4* outWt = (float4*)(out_W + (size_t)token * (NB * NB));

    // hj columns depend only on (lw & 7), NOT on k (m = k*64+lw, 64 % 8 == 0):
    // hoist the 4 column float4s out of the k loop.
    const int jb0 = (lw & 7) * 4;
    float4 hjv[4];
    #pragma unroll
    for (int e = 0; e < 4; ++e) {
        hjv[e] = *(const float4*)&shn[(jb0 + e) * 4];
    }

    #pragma unroll
    for (int k = 0; k < 4; ++k) {
        const int m  = k * 64 + lw;       // float4 index in token's W
        const int r  = m >> 3;            // row
        const float4 hr = *(const float4*)&shn[r * 4];
        const float  Lr = hr.w;
        const float* wp = (const float*)&wr[k];
        float4 res;
        float* resp = &res.x;
        #pragma unroll
        for (int e = 0; e < 4; ++e) {
            const int j = jb0 + e;
            const float4 hj = hjv[e];
            const float dx = hr.x - hj.x;
            const float dy = hr.y - hj.y;
            const float dz = hr.z - hj.z;
            const float dw = hr.w - hj.w;
            const float sq = dx * dx + dy * dy + dz * dz + dw * dw;
            const float dist = sqrtf(sq);               // sqrt(0)=0 matches ref
            const float mutual = 0.5f * (Lr + hj.w);
            float wn = 0.95f * wp[e] + 0.1f * mutual * dist;
            wn = clamp01(wn);
            resp[e] = (j == r) ? 0.0f : wn;             // zero diagonal
        }
        outWt[m] = res;                   // coalesced 1KB/instr store
    }
}

extern "C" void kernel_launch(void* const* d_in, const int* in_sizes, int n_in,
                              void* d_out, int out_size, void* d_ws, size_t ws_size,
                              hipStream_t stream) {
    const float* h    = (const float*)d_in[0];  // [8,2048,32,4]
    const float* W    = (const float*)d_in[1];  // [8,2048,32,32]
    const float* stim = (const float*)d_in[2];  // [8,2048,32]

    const int tokens = in_sizes[2] / NB;        // 16384
    float* out_h = (float*)d_out;               // [8,2048,32,4]
    float* out_W = (float*)d_out + (size_t)tokens * NB * 4;  // [8,2048,32,32]

    const int blocks = tokens / WAVES_PER_BLOCK; // 8192
    biotoken_step<<<blocks, 128, 0, stream>>>(h, W, stim, out_h, out_W);
}